// Round 6
// baseline (207.973 us; speedup 1.0000x reference)
//
#include <hip/hip_runtime.h>
#include <hip/hip_bf16.h>
#include <stdint.h>

#define DM    256
#define KC    4352   // 2048 + 1024 + 512 + 768
#define NCLS  26

typedef __bf16 bf16;
typedef __attribute__((ext_vector_type(8))) __bf16 bf16x8;
typedef __attribute__((ext_vector_type(4))) __bf16 bf16x4;
typedef __attribute__((ext_vector_type(4))) float f32x4;

// ---- workspace layout (bytes) ----
#define WCAT_OFF  0u          // 256*4352*2 = 2228224  (pre-swizzled)
#define P_OFF     2228224u    // 256*256*4  = 262144
#define CC_OFF    2490368u    // 1024
#define GT_OFF    2491392u    // 256*256*2  = 131072   (pre-swizzled)
#define G_OFF     2622464u    // 1024
#define BSUM_OFF  2623488u    // 1024
#define CS_OFF    2624512u    // 1024
#define CQ_OFF    2625536u    // 1024
#define SD_OFF    2626560u    // 1024
#define TD_OFF    2627584u    // 1024
#define FBAR_OFF  2628608u    // 16384*256*2 = 8388608 (pre-swizzled)
#define H_OFF     11017216u   // 16384*256*2 = 8388608 (bf16)

__device__ __forceinline__ bf16x8 cvt8(float4 a, float4 b) {
  bf16x8 r;
  r[0] = (bf16)a.x; r[1] = (bf16)a.y; r[2] = (bf16)a.z; r[3] = (bf16)a.w;
  r[4] = (bf16)b.x; r[5] = (bf16)b.y; r[6] = (bf16)b.z; r[7] = (bf16)b.w;
  return r;
}

__device__ __forceinline__ void gld_lds16(const void* g, void* l) {
  __builtin_amdgcn_global_load_lds(
      (const __attribute__((address_space(1))) void*)g,
      (__attribute__((address_space(3))) void*)l, 16, 0, 0);
}

__device__ __forceinline__ const float* pick(const float* x0, const float* x1,
                                             const float* x2, const float* x3,
                                             int k0, int& L, int& ko) {
  if (k0 < 2048)      { L = 2048; ko = k0;        return x0; }
  else if (k0 < 3072) { L = 1024; ko = k0 - 2048; return x1; }
  else if (k0 < 3584) { L = 512;  ko = k0 - 3072; return x2; }
  else                { L = 768;  ko = k0 - 3584; return x3; }
}

// ---- Pre12: Wcat (bf16, pre-swizzled chunks) + bsum + zero stats; and P/cc ----
__global__ __launch_bounds__(256) void k_pre12(
    const float* __restrict__ w0, const float* __restrict__ w1,
    const float* __restrict__ w2, const float* __restrict__ w3,
    const float* __restrict__ b0, const float* __restrict__ b1,
    const float* __restrict__ b2, const float* __restrict__ b3,
    const float* __restrict__ in_proj_w, const float* __restrict__ in_proj_b,
    const float* __restrict__ out_w, const float* __restrict__ out_b,
    bf16* __restrict__ Wcat, float* __restrict__ bsum,
    float* __restrict__ cs, float* __restrict__ cq,
    float* __restrict__ P, float* __restrict__ cc) {
  int bid = blockIdx.x;
  if (bid < 544) {                       // 544*256*8 == 256*4352 exactly
    int idx = bid * 256 + threadIdx.x;
    int e = idx * 8;
    int d = e / KC;
    int k = e - d * KC;
    const float* src; int o;
    if (k < 2048)      { src = w0 + d * 2048; o = k; }
    else if (k < 3072) { src = w1 + d * 1024; o = k - 2048; }
    else if (k < 3584) { src = w2 + d * 512;  o = k - 3072; }
    else               { src = w3 + d * 768;  o = k - 3584; }
    float4 a = *(const float4*)(src + o);
    float4 b = *(const float4*)(src + o + 4);
    // swizzle 8-elem chunk within its 64-elem k-tile: chunk ^= (row&7)
    int ks = (k & ~63) | ((((k >> 3) & 7) ^ (d & 7)) << 3);
    *(bf16x8*)(Wcat + (size_t)d * KC + ks) = cvt8(a, b);
  } else if (bid == 544) {
    int d = threadIdx.x;
    bsum[d] = b0[d] + b1[d] + b2[d] + b3[d];
    cs[d] = 0.f; cq[d] = 0.f;
  } else {
    int i = bid - 545;                   // 0..256
    int o = threadIdx.x;
    if (i < 256) {
      float s = 0.f;
      for (int j = 0; j < 256; ++j)
        s += in_proj_w[(512 + j) * 256 + i] * out_w[o * 256 + j];
      P[i * 256 + o] = s;
    } else {
      float s = 0.f;
      for (int j = 0; j < 256; ++j)
        s += in_proj_b[512 + j] * out_w[o * 256 + j];
      cc[o] = s + out_b[o];
    }
  }
}

// ---- Pre3: GT[j][i] = sum_o (P[i][o]+(i==o))*fc1_w[j][o], pre-swizzled; g[j] ----
__global__ __launch_bounds__(256) void k_pre3(
    const float* __restrict__ P, const float* __restrict__ cc,
    const float* __restrict__ fc1_w, const float* __restrict__ fc1_b,
    bf16* __restrict__ GT, float* __restrict__ g) {
  int j = blockIdx.x;
  int i = threadIdx.x;
  float s = 0.f;
  for (int o = 0; o < 256; ++o)
    s += (P[i * 256 + o] + (i == o ? 1.f : 0.f)) * fc1_w[j * 256 + o];
  int is = (i & ~63) | ((((i >> 3) & 7) ^ (j & 7)) << 3) | (i & 7);
  GT[j * 256 + is] = (bf16)s;
  if (i == 0) {
    float t = 0.f;
    for (int o = 0; o < 256; ++o) t += cc[o] * fc1_w[j * 256 + o];
    g[j] = t + fc1_b[j];
  }
}

// ---- K1: fbar = 0.25*(Xcat @ Wcat^T + bsum). BM=64 BN=256, BKo=256, BKi=64 ----
// DRAM-page-locality fix: A staged per OUTER 256-k tile => 1 KB contiguous
// per row (vs 256 B at BK=64), consecutive rows adjacent. Inner 4x64-k steps
// run the proven B dbuf pipeline. LDS 128 KB, 1 blk/CU (same occupancy as r3
// => isolates the burst-size variable).
__global__ __launch_bounds__(512, 2) void k_gemm1(
    const float* __restrict__ x0, const float* __restrict__ x1,
    const float* __restrict__ x2, const float* __restrict__ x3,
    const bf16* __restrict__ Wcat, const float* __restrict__ bsum,
    bf16* __restrict__ fbar) {
  __shared__ __align__(16) bf16 ldsA[2][16384];   // [buf][64 rows][256 k] 32 KB each
  __shared__ __align__(16) bf16 ldsB[2][16384];   // [buf][256 rows][64 k] 32 KB each
  int mt = blockIdx.x;                            // 256 blocks, 1 per CU
  int tid = threadIdx.x;
  int lane = tid & 63, wid = tid >> 6;
  int wr = wid >> 2, wc = wid & 3;                // 2x4 waves, wave tile 32x64
  int fr = lane & 15, fq = lane >> 4;
  f32x4 acc[2][4] = {};

  int arow = tid >> 3;                            // 0..63 (A row; also B base row)
  int ac0 = (tid & 7) * 4;                        // first of 4 8-elem chunks (0..31)
  const size_t bbase = (size_t)arow * KC + (tid & 7) * 8; // B rows arow + {0,64,128,192}
  const size_t xrow = (size_t)(mt * 64 + arow);

  float4 ra0, ra1, ra2, ra3, ra4, ra5, ra6, ra7;  // pending A(ko+1): 32 floats/thread

#define WRITE_A(buf)                                                          \
  do {                                                                        \
    *(bf16x8*)&ldsA[buf][arow * 256 + (((ac0 + 0) ^ (arow & 7)) << 3)] = cvt8(ra0, ra1); \
    *(bf16x8*)&ldsA[buf][arow * 256 + (((ac0 + 1) ^ (arow & 7)) << 3)] = cvt8(ra2, ra3); \
    *(bf16x8*)&ldsA[buf][arow * 256 + (((ac0 + 2) ^ (arow & 7)) << 3)] = cvt8(ra4, ra5); \
    *(bf16x8*)&ldsA[buf][arow * 256 + (((ac0 + 3) ^ (arow & 7)) << 3)] = cvt8(ra6, ra7); \
  } while (0)

  { // prologue: stage A(0) + B(0)
    int L, ko; const float* xs = pick(x0, x1, x2, x3, 0, L, ko);
    const float4* ap = (const float4*)(xs + xrow * L + ko) + (tid & 7) * 8;
    ra0 = ap[0]; ra1 = ap[1]; ra2 = ap[2]; ra3 = ap[3];
    ra4 = ap[4]; ra5 = ap[5]; ra6 = ap[6]; ra7 = ap[7];
#pragma unroll
    for (int j = 0; j < 4; ++j)
      gld_lds16(Wcat + bbase + (size_t)j * 64 * KC, &ldsB[0][tid * 8 + j * 4096]);
    WRITE_A(0);
    __syncthreads();
  }

  for (int ko = 0; ko < 17; ++ko) {
    if (ko < 16) {  // issue A(ko+1): 1 KB contiguous per row, rows adjacent
      int L, koff; const float* xs = pick(x0, x1, x2, x3, (ko + 1) * 256, L, koff);
      const float4* ap = (const float4*)(xs + xrow * L + koff) + (tid & 7) * 8;
      ra0 = ap[0]; ra1 = ap[1]; ra2 = ap[2]; ra3 = ap[3];
      ra4 = ap[4]; ra5 = ap[5]; ra6 = ap[6]; ra7 = ap[7];
    }
    const bf16* A = &ldsA[ko & 1][0];
#pragma unroll
    for (int ki = 0; ki < 4; ++ki) {
      int kt = ko * 4 + ki;
      if (kt < 67) {                              // B(kt+1) -> other slot
#pragma unroll
        for (int j = 0; j < 4; ++j)
          gld_lds16(Wcat + bbase + (size_t)(kt + 1) * 64 + (size_t)j * 64 * KC,
                    &ldsB[(kt + 1) & 1][tid * 8 + j * 4096]);
      }
      const bf16* Bb = &ldsB[kt & 1][0];
      bf16x8 av[2][2], bv[4][2];
#pragma unroll
      for (int m = 0; m < 2; ++m) {
        int row = wr * 32 + m * 16 + fr;
#pragma unroll
        for (int kk = 0; kk < 2; ++kk) {
          int c = ki * 8 + (kk << 2) + fq;
          av[m][kk] = *(const bf16x8*)(A + row * 256 + ((c ^ (row & 7)) << 3));
        }
      }
#pragma unroll
      for (int n = 0; n < 4; ++n) {
        int row = wc * 64 + n * 16 + fr;
#pragma unroll
        for (int kk = 0; kk < 2; ++kk)
          bv[n][kk] = *(const bf16x8*)(Bb + row * 64 + ((((kk << 2) | fq) ^ (row & 7)) << 3));
      }
#pragma unroll
      for (int kk = 0; kk < 2; ++kk)
#pragma unroll
        for (int m = 0; m < 2; ++m)
#pragma unroll
          for (int n = 0; n < 4; ++n)
            acc[m][n] = __builtin_amdgcn_mfma_f32_16x16x32_bf16(av[m][kk], bv[n][kk], acc[m][n], 0, 0, 0);
      __builtin_amdgcn_sched_barrier(0);          // keep A/B staging after MFMA
      if (ki == 3 && ko < 16)
        WRITE_A((ko + 1) & 1);
      __syncthreads();
    }
  }

#pragma unroll
  for (int n = 0; n < 4; ++n) {
    int col = wc * 64 + n * 16 + fr;
    float bs = bsum[col];
#pragma unroll
    for (int m = 0; m < 2; ++m) {
      int row0 = mt * 64 + wr * 32 + m * 16 + fq * 4;
#pragma unroll
      for (int r = 0; r < 4; ++r) {
        int row = row0 + r;
        int csw = (col & ~63) | ((((col >> 3) & 7) ^ (row & 7)) << 3) | (col & 7);
        fbar[(size_t)row * DM + csw] = (bf16)(0.25f * (acc[m][n][r] + bs));
      }
    }
  }
#undef WRITE_A
}

// ---- K2: h = fbar @ GT^T + g (bf16 out) + column stats. K=256, 4 dbuf steps ----
__global__ __launch_bounds__(256, 4) void k_gemm2(
    const bf16* __restrict__ fbar, const bf16* __restrict__ GT,
    const float* __restrict__ g, bf16* __restrict__ h,
    float* __restrict__ cs, float* __restrict__ cq) {
  __shared__ __align__(16) bf16 lds[2][8192];
  int bid = blockIdx.x;
  int tile = (bid & 7) * 128 + (bid >> 3);
  int mt = tile >> 2, nt = tile & 3;
  int tid = threadIdx.x;
  int lane = tid & 63, wid = tid >> 6;
  int wr = wid >> 1, wc = wid & 1;
  int fr = lane & 15, fq = lane >> 4;
  f32x4 acc[2][2] = {};

  const size_t arow0 = (size_t)(mt * 64 + (tid >> 3)) * DM + (tid & 7) * 8;
  const size_t arow1 = (size_t)(mt * 64 + 32 + (tid >> 3)) * DM + (tid & 7) * 8;
  const size_t grow0 = (size_t)(nt * 64 + (tid >> 3)) * DM + (tid & 7) * 8;
  const size_t grow1 = (size_t)(nt * 64 + 32 + (tid >> 3)) * DM + (tid & 7) * 8;

  gld_lds16(fbar + arow0, &lds[0][tid * 8]);
  gld_lds16(fbar + arow1, &lds[0][2048 + tid * 8]);
  gld_lds16(GT + grow0, &lds[0][4096 + tid * 8]);
  gld_lds16(GT + grow1, &lds[0][4096 + 2048 + tid * 8]);
  __syncthreads();

  for (int kt = 0; kt < 4; ++kt) {
    int cur = kt & 1;
    if (kt < 3) {
      int k0 = (kt + 1) * 64;
      gld_lds16(fbar + arow0 + k0, &lds[cur ^ 1][tid * 8]);
      gld_lds16(fbar + arow1 + k0, &lds[cur ^ 1][2048 + tid * 8]);
      gld_lds16(GT + grow0 + k0, &lds[cur ^ 1][4096 + tid * 8]);
      gld_lds16(GT + grow1 + k0, &lds[cur ^ 1][4096 + 2048 + tid * 8]);
    }
    const bf16* A  = &lds[cur][0];
    const bf16* Bb = &lds[cur][4096];
    bf16x8 av[2][2], bv[2][2];
#pragma unroll
    for (int m = 0; m < 2; ++m) {
      int row = wr * 32 + m * 16 + fr;
#pragma unroll
      for (int kk = 0; kk < 2; ++kk)
        av[m][kk] = *(const bf16x8*)(A + row * 64 + ((((kk << 2) | fq) ^ (row & 7)) << 3));
    }
#pragma unroll
    for (int n = 0; n < 2; ++n) {
      int row = wc * 32 + n * 16 + fr;
#pragma unroll
      for (int kk = 0; kk < 2; ++kk)
        bv[n][kk] = *(const bf16x8*)(Bb + row * 64 + ((((kk << 2) | fq) ^ (row & 7)) << 3));
    }
#pragma unroll
    for (int kk = 0; kk < 2; ++kk)
#pragma unroll
      for (int m = 0; m < 2; ++m)
#pragma unroll
        for (int n = 0; n < 2; ++n)
          acc[m][n] = __builtin_amdgcn_mfma_f32_16x16x32_bf16(av[m][kk], bv[n][kk], acc[m][n], 0, 0, 0);
    __syncthreads();
  }

#pragma unroll
  for (int n = 0; n < 2; ++n) {
    int col = nt * 64 + wc * 32 + n * 16 + fr;
    float gv = g[col];
    float s = 0.f, q = 0.f;
#pragma unroll
    for (int m = 0; m < 2; ++m) {
      int row0 = mt * 64 + wr * 32 + m * 16 + fq * 4;
#pragma unroll
      for (int r = 0; r < 4; ++r) {
        float v = acc[m][n][r] + gv;
        h[(size_t)(row0 + r) * DM + col] = (bf16)v;
        s += v; q += v * v;
      }
    }
    s += __shfl_xor(s, 16); s += __shfl_xor(s, 32);
    q += __shfl_xor(q, 16); q += __shfl_xor(q, 32);
    if (fq == 0) { atomicAdd(&cs[col], s); atomicAdd(&cq[col], q); }
  }
}

// ---- stats finalize ----
__global__ void k_stats(const float* __restrict__ cs, const float* __restrict__ cq,
                        const float* __restrict__ bn_g, const float* __restrict__ bn_b,
                        float* __restrict__ sd, float* __restrict__ td) {
  int d = threadIdx.x;
  float mu = cs[d] * (1.f / 16384.f);
  float var = cq[d] * (1.f / 16384.f) - mu * mu;
  float s = bn_g[d] * rsqrtf(var + 1e-5f);
  sd[d] = s;
  td[d] = bn_b[d] - mu * s;
}

// ---- K3: out = relu(h*s + t) @ fc2^T + fc2_b ----
__global__ __launch_bounds__(256) void k_fc2(
    const bf16* __restrict__ h, const float* __restrict__ sd, const float* __restrict__ td,
    const float* __restrict__ fc2_w, const float* __restrict__ fc2_b,
    float* __restrict__ out) {
  int wid = threadIdx.x >> 6, lane = threadIdx.x & 63;
  int row = blockIdx.x * 4 + wid;
  bf16x4 hv = *(const bf16x4*)(h + (size_t)row * 256 + lane * 4);
  float4 s = *(const float4*)(sd + lane * 4);
  float4 t = *(const float4*)(td + lane * 4);
  float y0 = fmaxf((float)hv[0] * s.x + t.x, 0.f);
  float y1 = fmaxf((float)hv[1] * s.y + t.y, 0.f);
  float y2 = fmaxf((float)hv[2] * s.z + t.z, 0.f);
  float y3 = fmaxf((float)hv[3] * s.w + t.w, 0.f);
  for (int c = 0; c < NCLS; ++c) {
    float4 w = *(const float4*)(fc2_w + c * 256 + lane * 4);
    float p = y0 * w.x + y1 * w.y + y2 * w.z + y3 * w.w;
#pragma unroll
    for (int off = 32; off; off >>= 1) p += __shfl_xor(p, off);
    if (lane == 0) out[row * NCLS + c] = p + fc2_b[c];
  }
}

extern "C" void kernel_launch(void* const* d_in, const int* in_sizes, int n_in,
                              void* d_out, int out_size, void* d_ws, size_t ws_size,
                              hipStream_t stream) {
  (void)in_sizes; (void)n_in; (void)out_size; (void)ws_size;
  const float* x0 = (const float*)d_in[0];
  const float* x1 = (const float*)d_in[1];
  const float* x2 = (const float*)d_in[2];
  const float* x3 = (const float*)d_in[3];
  const float* w0 = (const float*)d_in[4];
  const float* b0 = (const float*)d_in[5];
  const float* w1 = (const float*)d_in[6];
  const float* b1 = (const float*)d_in[7];
  const float* w2 = (const float*)d_in[8];
  const float* b2 = (const float*)d_in[9];
  const float* w3 = (const float*)d_in[10];
  const float* b3 = (const float*)d_in[11];
  const float* in_proj_w = (const float*)d_in[12];
  const float* in_proj_b = (const float*)d_in[13];
  const float* out_w = (const float*)d_in[14];
  const float* out_b = (const float*)d_in[15];
  // gate (16..19) is mathematically dead: feats_cross == feats_self
  const float* fc1_w = (const float*)d_in[20];
  const float* fc1_b = (const float*)d_in[21];
  const float* bn_g = (const float*)d_in[22];
  const float* bn_b = (const float*)d_in[23];
  const float* fc2_w = (const float*)d_in[24];
  const float* fc2_b = (const float*)d_in[25];

  char* ws = (char*)d_ws;
  bf16* Wcat = (bf16*)(ws + WCAT_OFF);
  float* P   = (float*)(ws + P_OFF);
  float* cc  = (float*)(ws + CC_OFF);
  bf16* GT   = (bf16*)(ws + GT_OFF);
  float* g   = (float*)(ws + G_OFF);
  float* bsum= (float*)(ws + BSUM_OFF);
  float* cs  = (float*)(ws + CS_OFF);
  float* cq  = (float*)(ws + CQ_OFF);
  float* sd  = (float*)(ws + SD_OFF);
  float* td  = (float*)(ws + TD_OFF);
  bf16* fbar = (bf16*)(ws + FBAR_OFF);
  bf16* h    = (bf16*)(ws + H_OFF);
  float* out = (float*)d_out;

  k_pre12<<<dim3(802), dim3(256), 0, stream>>>(w0, w1, w2, w3, b0, b1, b2, b3,
                                               in_proj_w, in_proj_b, out_w, out_b,
                                               Wcat, bsum, cs, cq, P, cc);
  k_pre3<<<dim3(256), dim3(256), 0, stream>>>(P, cc, fc1_w, fc1_b, GT, g);
  k_gemm1<<<dim3(256), dim3(512), 0, stream>>>(x0, x1, x2, x3, Wcat, bsum, fbar);
  k_gemm2<<<dim3(1024), dim3(256), 0, stream>>>(fbar, GT, g, h, cs, cq);
  k_stats<<<dim3(1), dim3(256), 0, stream>>>(cs, cq, bn_g, bn_b, sd, td);
  k_fc2<<<dim3(4096), dim3(256), 0, stream>>>(h, sd, td, fc2_w, fc2_b, out);
}

// Round 7
// 203.817 us; speedup vs baseline: 1.0204x; 1.0204x over previous
//
#include <hip/hip_runtime.h>
#include <hip/hip_bf16.h>
#include <stdint.h>

#define DM    256
#define KC    4352   // 2048 + 1024 + 512 + 768
#define NCLS  26

typedef __bf16 bf16;
typedef __attribute__((ext_vector_type(8))) __bf16 bf16x8;
typedef __attribute__((ext_vector_type(4))) __bf16 bf16x4;
typedef __attribute__((ext_vector_type(4))) float f32x4;

// ---- workspace layout (bytes) ----
#define WCAT_OFF  0u          // 256*4352*2 = 2228224  (pre-swizzled)
#define P_OFF     2228224u    // 256*256*4  = 262144
#define CC_OFF    2490368u    // 1024
#define GT_OFF    2491392u    // 256*256*2  = 131072   (pre-swizzled)
#define G_OFF     2622464u    // 1024
#define BSUM_OFF  2623488u    // 1024
#define CS_OFF    2624512u    // 1024
#define CQ_OFF    2625536u    // 1024
#define SD_OFF    2626560u    // 1024
#define TD_OFF    2627584u    // 1024
#define FBAR_OFF  2628608u    // 16384*256*2 = 8388608 (pre-swizzled)
#define H_OFF     11017216u   // 16384*256*2 = 8388608 (bf16)

__device__ __forceinline__ bf16x8 cvt8(float4 a, float4 b) {
  bf16x8 r;
  r[0] = (bf16)a.x; r[1] = (bf16)a.y; r[2] = (bf16)a.z; r[3] = (bf16)a.w;
  r[4] = (bf16)b.x; r[5] = (bf16)b.y; r[6] = (bf16)b.z; r[7] = (bf16)b.w;
  return r;
}

__device__ __forceinline__ void gld_lds16(const void* g, void* l) {
  __builtin_amdgcn_global_load_lds(
      (const __attribute__((address_space(1))) void*)g,
      (__attribute__((address_space(3))) void*)l, 16, 0, 0);
}

__device__ __forceinline__ const float* pick(const float* x0, const float* x1,
                                             const float* x2, const float* x3,
                                             int k0, int& L, int& ko) {
  if (k0 < 2048)      { L = 2048; ko = k0;        return x0; }
  else if (k0 < 3072) { L = 1024; ko = k0 - 2048; return x1; }
  else if (k0 < 3584) { L = 512;  ko = k0 - 3072; return x2; }
  else                { L = 768;  ko = k0 - 3584; return x3; }
}

// ---- Pre12: Wcat (bf16, pre-swizzled chunks) + bsum + zero stats; and P/cc ----
__global__ __launch_bounds__(256) void k_pre12(
    const float* __restrict__ w0, const float* __restrict__ w1,
    const float* __restrict__ w2, const float* __restrict__ w3,
    const float* __restrict__ b0, const float* __restrict__ b1,
    const float* __restrict__ b2, const float* __restrict__ b3,
    const float* __restrict__ in_proj_w, const float* __restrict__ in_proj_b,
    const float* __restrict__ out_w, const float* __restrict__ out_b,
    bf16* __restrict__ Wcat, float* __restrict__ bsum,
    float* __restrict__ cs, float* __restrict__ cq,
    float* __restrict__ P, float* __restrict__ cc) {
  int bid = blockIdx.x;
  if (bid < 544) {                       // 544*256*8 == 256*4352 exactly
    int idx = bid * 256 + threadIdx.x;
    int e = idx * 8;
    int d = e / KC;
    int k = e - d * KC;
    const float* src; int o;
    if (k < 2048)      { src = w0 + d * 2048; o = k; }
    else if (k < 3072) { src = w1 + d * 1024; o = k - 2048; }
    else if (k < 3584) { src = w2 + d * 512;  o = k - 3072; }
    else               { src = w3 + d * 768;  o = k - 3584; }
    float4 a = *(const float4*)(src + o);
    float4 b = *(const float4*)(src + o + 4);
    // swizzle 8-elem chunk within its 64-elem k-tile: chunk ^= (row&7)
    int ks = (k & ~63) | ((((k >> 3) & 7) ^ (d & 7)) << 3);
    *(bf16x8*)(Wcat + (size_t)d * KC + ks) = cvt8(a, b);
  } else if (bid == 544) {
    int d = threadIdx.x;
    bsum[d] = b0[d] + b1[d] + b2[d] + b3[d];
    cs[d] = 0.f; cq[d] = 0.f;
  } else {
    int i = bid - 545;                   // 0..256
    int o = threadIdx.x;
    if (i < 256) {
      float s = 0.f;
      for (int j = 0; j < 256; ++j)
        s += in_proj_w[(512 + j) * 256 + i] * out_w[o * 256 + j];
      P[i * 256 + o] = s;
    } else {
      float s = 0.f;
      for (int j = 0; j < 256; ++j)
        s += in_proj_b[512 + j] * out_w[o * 256 + j];
      cc[o] = s + out_b[o];
    }
  }
}

// ---- Pre3: GT[j][i] = sum_o (P[i][o]+(i==o))*fc1_w[j][o], pre-swizzled; g[j] ----
__global__ __launch_bounds__(256) void k_pre3(
    const float* __restrict__ P, const float* __restrict__ cc,
    const float* __restrict__ fc1_w, const float* __restrict__ fc1_b,
    bf16* __restrict__ GT, float* __restrict__ g) {
  int j = blockIdx.x;
  int i = threadIdx.x;
  float s = 0.f;
  for (int o = 0; o < 256; ++o)
    s += (P[i * 256 + o] + (i == o ? 1.f : 0.f)) * fc1_w[j * 256 + o];
  int is = (i & ~63) | ((((i >> 3) & 7) ^ (j & 7)) << 3) | (i & 7);
  GT[j * 256 + is] = (bf16)s;
  if (i == 0) {
    float t = 0.f;
    for (int o = 0; o < 256; ++o) t += cc[o] * fc1_w[j * 256 + o];
    g[j] = t + fc1_b[j];
  }
}

// ---- K1: fbar = 0.25*(Xcat @ Wcat^T + bsum). BM=64 BN=256 BK=64 ----
// ALL loop loads are global_load_lds (A staged as raw fp32, cvt in regs).
// Tri-buffered slots, depth-2 in flight, counted vmcnt(12) waits only for
// loads issued two iterations ago. Raw s_barrier (no vmcnt(0) drain).
__global__ __launch_bounds__(512, 2) void k_gemm1(
    const float* __restrict__ x0, const float* __restrict__ x1,
    const float* __restrict__ x2, const float* __restrict__ x3,
    const bf16* __restrict__ Wcat, const float* __restrict__ bsum,
    bf16* __restrict__ fbar) {
  __shared__ __align__(16) float ldsA[3][4096];   // 64x64 f32, 16 KB/slot
  __shared__ __align__(16) bf16 ldsB[3][16384];   // 256x64 bf16, 32 KB/slot
  int mt = blockIdx.x;                            // 256 blocks, 1 per CU
  int tid = threadIdx.x;
  int lane = tid & 63, wid = tid >> 6;
  int wr = wid >> 2, wc = wid & 3;                // 2x4 waves, wave tile 32x64
  int fr = lane & 15, fq = lane >> 4;
  f32x4 acc[2][4] = {};

  // A staging (fp32, 16-slot XOR swizzle ch^(row&15); dest linear, src inv-swz)
  int ar0 = tid >> 4;                             // rows ar0 and ar0+32
  int acol = ((tid & 15) ^ (ar0 & 15)) << 2;      // f32 col (same for both rows)
  // B staging (bf16, pre-swizzled Wcat; dest linear) — r3-proven
  const size_t bbase = (size_t)(tid >> 3) * KC + (tid & 7) * 8;

#define ISSUE_TILE(k0, slot)                                                   \
  do {                                                                         \
    int L_, ko_; const float* xs_ = pick(x0, x1, x2, x3, (k0), L_, ko_);       \
    const float* s0_ = xs_ + (size_t)(mt * 64 + ar0) * L_ + ko_ + acol;        \
    gld_lds16(s0_,                 &ldsA[slot][tid * 4]);                      \
    gld_lds16(s0_ + (size_t)32 * L_, &ldsA[slot][2048 + tid * 4]);             \
    _Pragma("unroll")                                                          \
    for (int j_ = 0; j_ < 4; ++j_)                                             \
      gld_lds16(Wcat + bbase + (k0) + (size_t)j_ * 64 * KC,                    \
                &ldsB[slot][tid * 8 + j_ * 4096]);                             \
  } while (0)

  // prologue: tiles 0 and 1 in flight
  ISSUE_TILE(0, 0);
  ISSUE_TILE(64, 1);

  int slot = 0;
  for (int t = 0; t < 68; ++t) {
    // issue tile t+2 into slot (t+2)%3 (== (t-1)%3, protected by t-1 end barrier)
    if (t < 66) {
      int slot2 = slot + 2; if (slot2 >= 3) slot2 -= 3;
      ISSUE_TILE((t + 2) * 64, slot2);
    }
    // wait for tile t's 6 gld_lds (12 newer ops from t+1,t+2 stay in flight)
    if (t < 66)      asm volatile("s_waitcnt vmcnt(12)" ::: "memory");
    else if (t == 66) asm volatile("s_waitcnt vmcnt(6)" ::: "memory");
    else              asm volatile("s_waitcnt vmcnt(0)" ::: "memory");
    __builtin_amdgcn_s_barrier();                 // tile t visible to all waves
    __builtin_amdgcn_sched_barrier(0);

    const float* A = &ldsA[slot][0];
    const bf16* Bb = &ldsB[slot][0];
    bf16x8 av[2][2], bv[4][2];
#pragma unroll
    for (int m = 0; m < 2; ++m) {
      int row = wr * 32 + m * 16 + fr;
#pragma unroll
      for (int kk = 0; kk < 2; ++kk) {
        int ch = (kk << 3) | (fq << 1);
        float4 lo = *(const float4*)(A + row * 64 + ((ch ^ (row & 15)) << 2));
        float4 hi = *(const float4*)(A + row * 64 + (((ch | 1) ^ (row & 15)) << 2));
        av[m][kk] = cvt8(lo, hi);
      }
    }
#pragma unroll
    for (int n = 0; n < 4; ++n) {
      int row = wc * 64 + n * 16 + fr;
#pragma unroll
      for (int kk = 0; kk < 2; ++kk)
        bv[n][kk] = *(const bf16x8*)(Bb + row * 64 + ((((kk << 2) | fq) ^ (row & 7)) << 3));
    }
#pragma unroll
    for (int kk = 0; kk < 2; ++kk)
#pragma unroll
      for (int m = 0; m < 2; ++m)
#pragma unroll
        for (int n = 0; n < 4; ++n)
          acc[m][n] = __builtin_amdgcn_mfma_f32_16x16x32_bf16(av[m][kk], bv[n][kk], acc[m][n], 0, 0, 0);
    __builtin_amdgcn_sched_barrier(0);
    __builtin_amdgcn_s_barrier();                 // all waves done with slot
    if (++slot == 3) slot = 0;
  }
#undef ISSUE_TILE

#pragma unroll
  for (int n = 0; n < 4; ++n) {
    int col = wc * 64 + n * 16 + fr;
    float bs = bsum[col];
#pragma unroll
    for (int m = 0; m < 2; ++m) {
      int row0 = mt * 64 + wr * 32 + m * 16 + fq * 4;
#pragma unroll
      for (int r = 0; r < 4; ++r) {
        int row = row0 + r;
        int csw = (col & ~63) | ((((col >> 3) & 7) ^ (row & 7)) << 3) | (col & 7);
        fbar[(size_t)row * DM + csw] = (bf16)(0.25f * (acc[m][n][r] + bs));
      }
    }
  }
}

// ---- K2: h = fbar @ GT^T + g (bf16 out) + column stats. K=256, 4 dbuf steps ----
__global__ __launch_bounds__(256, 4) void k_gemm2(
    const bf16* __restrict__ fbar, const bf16* __restrict__ GT,
    const float* __restrict__ g, bf16* __restrict__ h,
    float* __restrict__ cs, float* __restrict__ cq) {
  __shared__ __align__(16) bf16 lds[2][8192];
  int bid = blockIdx.x;
  int tile = (bid & 7) * 128 + (bid >> 3);
  int mt = tile >> 2, nt = tile & 3;
  int tid = threadIdx.x;
  int lane = tid & 63, wid = tid >> 6;
  int wr = wid >> 1, wc = wid & 1;
  int fr = lane & 15, fq = lane >> 4;
  f32x4 acc[2][2] = {};

  const size_t arow0 = (size_t)(mt * 64 + (tid >> 3)) * DM + (tid & 7) * 8;
  const size_t arow1 = (size_t)(mt * 64 + 32 + (tid >> 3)) * DM + (tid & 7) * 8;
  const size_t grow0 = (size_t)(nt * 64 + (tid >> 3)) * DM + (tid & 7) * 8;
  const size_t grow1 = (size_t)(nt * 64 + 32 + (tid >> 3)) * DM + (tid & 7) * 8;

  gld_lds16(fbar + arow0, &lds[0][tid * 8]);
  gld_lds16(fbar + arow1, &lds[0][2048 + tid * 8]);
  gld_lds16(GT + grow0, &lds[0][4096 + tid * 8]);
  gld_lds16(GT + grow1, &lds[0][4096 + 2048 + tid * 8]);
  __syncthreads();

  for (int kt = 0; kt < 4; ++kt) {
    int cur = kt & 1;
    if (kt < 3) {
      int k0 = (kt + 1) * 64;
      gld_lds16(fbar + arow0 + k0, &lds[cur ^ 1][tid * 8]);
      gld_lds16(fbar + arow1 + k0, &lds[cur ^ 1][2048 + tid * 8]);
      gld_lds16(GT + grow0 + k0, &lds[cur ^ 1][4096 + tid * 8]);
      gld_lds16(GT + grow1 + k0, &lds[cur ^ 1][4096 + 2048 + tid * 8]);
    }
    const bf16* A  = &lds[cur][0];
    const bf16* Bb = &lds[cur][4096];
    bf16x8 av[2][2], bv[2][2];
#pragma unroll
    for (int m = 0; m < 2; ++m) {
      int row = wr * 32 + m * 16 + fr;
#pragma unroll
      for (int kk = 0; kk < 2; ++kk)
        av[m][kk] = *(const bf16x8*)(A + row * 64 + ((((kk << 2) | fq) ^ (row & 7)) << 3));
    }
#pragma unroll
    for (int n = 0; n < 2; ++n) {
      int row = wc * 32 + n * 16 + fr;
#pragma unroll
      for (int kk = 0; kk < 2; ++kk)
        bv[n][kk] = *(const bf16x8*)(Bb + row * 64 + ((((kk << 2) | fq) ^ (row & 7)) << 3));
    }
#pragma unroll
    for (int kk = 0; kk < 2; ++kk)
#pragma unroll
      for (int m = 0; m < 2; ++m)
#pragma unroll
        for (int n = 0; n < 2; ++n)
          acc[m][n] = __builtin_amdgcn_mfma_f32_16x16x32_bf16(av[m][kk], bv[n][kk], acc[m][n], 0, 0, 0);
    __syncthreads();
  }

#pragma unroll
  for (int n = 0; n < 2; ++n) {
    int col = nt * 64 + wc * 32 + n * 16 + fr;
    float gv = g[col];
    float s = 0.f, q = 0.f;
#pragma unroll
    for (int m = 0; m < 2; ++m) {
      int row0 = mt * 64 + wr * 32 + m * 16 + fq * 4;
#pragma unroll
      for (int r = 0; r < 4; ++r) {
        float v = acc[m][n][r] + gv;
        h[(size_t)(row0 + r) * DM + col] = (bf16)v;
        s += v; q += v * v;
      }
    }
    s += __shfl_xor(s, 16); s += __shfl_xor(s, 32);
    q += __shfl_xor(q, 16); q += __shfl_xor(q, 32);
    if (fq == 0) { atomicAdd(&cs[col], s); atomicAdd(&cq[col], q); }
  }
}

// ---- stats finalize ----
__global__ void k_stats(const float* __restrict__ cs, const float* __restrict__ cq,
                        const float* __restrict__ bn_g, const float* __restrict__ bn_b,
                        float* __restrict__ sd, float* __restrict__ td) {
  int d = threadIdx.x;
  float mu = cs[d] * (1.f / 16384.f);
  float var = cq[d] * (1.f / 16384.f) - mu * mu;
  float s = bn_g[d] * rsqrtf(var + 1e-5f);
  sd[d] = s;
  td[d] = bn_b[d] - mu * s;
}

// ---- K3: out = relu(h*s + t) @ fc2^T + fc2_b ----
__global__ __launch_bounds__(256) void k_fc2(
    const bf16* __restrict__ h, const float* __restrict__ sd, const float* __restrict__ td,
    const float* __restrict__ fc2_w, const float* __restrict__ fc2_b,
    float* __restrict__ out) {
  int wid = threadIdx.x >> 6, lane = threadIdx.x & 63;
  int row = blockIdx.x * 4 + wid;
  bf16x4 hv = *(const bf16x4*)(h + (size_t)row * 256 + lane * 4);
  float4 s = *(const float4*)(sd + lane * 4);
  float4 t = *(const float4*)(td + lane * 4);
  float y0 = fmaxf((float)hv[0] * s.x + t.x, 0.f);
  float y1 = fmaxf((float)hv[1] * s.y + t.y, 0.f);
  float y2 = fmaxf((float)hv[2] * s.z + t.z, 0.f);
  float y3 = fmaxf((float)hv[3] * s.w + t.w, 0.f);
  for (int c = 0; c < NCLS; ++c) {
    float4 w = *(const float4*)(fc2_w + c * 256 + lane * 4);
    float p = y0 * w.x + y1 * w.y + y2 * w.z + y3 * w.w;
#pragma unroll
    for (int off = 32; off; off >>= 1) p += __shfl_xor(p, off);
    if (lane == 0) out[row * NCLS + c] = p + fc2_b[c];
  }
}

extern "C" void kernel_launch(void* const* d_in, const int* in_sizes, int n_in,
                              void* d_out, int out_size, void* d_ws, size_t ws_size,
                              hipStream_t stream) {
  (void)in_sizes; (void)n_in; (void)out_size; (void)ws_size;
  const float* x0 = (const float*)d_in[0];
  const float* x1 = (const float*)d_in[1];
  const float* x2 = (const float*)d_in[2];
  const float* x3 = (const float*)d_in[3];
  const float* w0 = (const float*)d_in[4];
  const float* b0 = (const float*)d_in[5];
  const float* w1 = (const float*)d_in[6];
  const float* b1 = (const float*)d_in[7];
  const float* w2 = (const float*)d_in[8];
  const float* b2 = (const float*)d_in[9];
  const float* w3 = (const float*)d_in[10];
  const float* b3 = (const float*)d_in[11];
  const float* in_proj_w = (const float*)d_in[12];
  const float* in_proj_b = (const float*)d_in[13];
  const float* out_w = (const float*)d_in[14];
  const float* out_b = (const float*)d_in[15];
  // gate (16..19) is mathematically dead: feats_cross == feats_self
  const float* fc1_w = (const float*)d_in[20];
  const float* fc1_b = (const float*)d_in[21];
  const float* bn_g = (const float*)d_in[22];
  const float* bn_b = (const float*)d_in[23];
  const float* fc2_w = (const float*)d_in[24];
  const float* fc2_b = (const float*)d_in[25];

  char* ws = (char*)d_ws;
  bf16* Wcat = (bf16*)(ws + WCAT_OFF);
  float* P   = (float*)(ws + P_OFF);
  float* cc  = (float*)(ws + CC_OFF);
  bf16* GT   = (bf16*)(ws + GT_OFF);
  float* g   = (float*)(ws + G_OFF);
  float* bsum= (float*)(ws + BSUM_OFF);
  float* cs  = (float*)(ws + CS_OFF);
  float* cq  = (float*)(ws + CQ_OFF);
  float* sd  = (float*)(ws + SD_OFF);
  float* td  = (float*)(ws + TD_OFF);
  bf16* fbar = (bf16*)(ws + FBAR_OFF);
  bf16* h    = (bf16*)(ws + H_OFF);
  float* out = (float*)d_out;

  k_pre12<<<dim3(802), dim3(256), 0, stream>>>(w0, w1, w2, w3, b0, b1, b2, b3,
                                               in_proj_w, in_proj_b, out_w, out_b,
                                               Wcat, bsum, cs, cq, P, cc);
  k_pre3<<<dim3(256), dim3(256), 0, stream>>>(P, cc, fc1_w, fc1_b, GT, g);
  k_gemm1<<<dim3(256), dim3(512), 0, stream>>>(x0, x1, x2, x3, Wcat, bsum, fbar);
  k_gemm2<<<dim3(1024), dim3(256), 0, stream>>>(fbar, GT, g, h, cs, cq);
  k_stats<<<dim3(1), dim3(256), 0, stream>>>(cs, cq, bn_g, bn_b, sd, td);
  k_fc2<<<dim3(4096), dim3(256), 0, stream>>>(h, sd, td, fc2_w, fc2_b, out);
}

// Round 9
// 164.630 us; speedup vs baseline: 1.2633x; 1.2380x over previous
//
#include <hip/hip_runtime.h>
#include <hip/hip_bf16.h>
#include <stdint.h>

#define DM    256
#define KC    4352   // 2048 + 1024 + 512 + 768
#define NCLS  26

typedef __bf16 bf16;
typedef __attribute__((ext_vector_type(8))) __bf16 bf16x8;
typedef __attribute__((ext_vector_type(4))) __bf16 bf16x4;
typedef __attribute__((ext_vector_type(4))) float f32x4;

// ---- workspace layout (bytes) ----
#define WPACK_OFF 0u          // 256*4352*2 = 2228224  (MFMA-fragment-ordered)
#define P_OFF     2228224u    // 256*256*4  = 262144
#define CC_OFF    2490368u    // 1024
#define GT_OFF    2491392u    // 256*256*2  = 131072   (pre-swizzled)
#define G_OFF     2622464u    // 1024
#define BSUM_OFF  2623488u    // 1024
#define CS_OFF    2624512u    // 1024
#define CQ_OFF    2625536u    // 1024
#define SD_OFF    2626560u    // 1024
#define TD_OFF    2627584u    // 1024
#define FBAR_OFF  2628608u    // 16384*256*2 = 8388608 (pre-swizzled)
#define H_OFF     11017216u   // 16384*256*2 = 8388608 (bf16)

__device__ __forceinline__ bf16x8 cvt8(float4 a, float4 b) {
  bf16x8 r;
  r[0] = (bf16)a.x; r[1] = (bf16)a.y; r[2] = (bf16)a.z; r[3] = (bf16)a.w;
  r[4] = (bf16)b.x; r[5] = (bf16)b.y; r[6] = (bf16)b.z; r[7] = (bf16)b.w;
  return r;
}

__device__ __forceinline__ void gld_lds16(const void* g, void* l) {
  __builtin_amdgcn_global_load_lds(
      (const __attribute__((address_space(1))) void*)g,
      (__attribute__((address_space(3))) void*)l, 16, 0, 0);
}

__device__ __forceinline__ const float* pick(const float* x0, const float* x1,
                                             const float* x2, const float* x3,
                                             int k0, int& L, int& ko) {
  if (k0 < 2048)      { L = 2048; ko = k0;        return x0; }
  else if (k0 < 3072) { L = 1024; ko = k0 - 2048; return x1; }
  else if (k0 < 3584) { L = 512;  ko = k0 - 3072; return x2; }
  else                { L = 768;  ko = k0 - 3584; return x3; }
}

// ---- Pre12: Wpack (bf16, MFMA-fragment order) + bsum + zero stats; and P/cc ----
// Wpack unit u (16 B = 8 bf16), u in [0, 139264): u = ((n16*68 + kt)*2 + kk)*64 + lane
//   holds W[n16*16 + (lane&15)][kt*64 + kk*32 + (lane>>4)*8 .. +8]
__global__ __launch_bounds__(256) void k_pre12(
    const float* __restrict__ w0, const float* __restrict__ w1,
    const float* __restrict__ w2, const float* __restrict__ w3,
    const float* __restrict__ b0, const float* __restrict__ b1,
    const float* __restrict__ b2, const float* __restrict__ b3,
    const float* __restrict__ in_proj_w, const float* __restrict__ in_proj_b,
    const float* __restrict__ out_w, const float* __restrict__ out_b,
    bf16* __restrict__ Wpack, float* __restrict__ bsum,
    float* __restrict__ cs, float* __restrict__ cq,
    float* __restrict__ P, float* __restrict__ cc) {
  int bid = blockIdx.x;
  if (bid < 544) {                       // 544*256 = 139264 units = 256*4352*2B/16B
    int u = bid * 256 + threadIdx.x;
    int lane = u & 63;
    int q = u >> 6;                      // [0, 2176)
    int kk = q & 1; q >>= 1;             // [0, 1088)
    int kt = q % 68;
    int n16 = q / 68;                    // [0, 16)
    int row = n16 * 16 + (lane & 15);
    int k = kt * 64 + kk * 32 + (lane >> 4) * 8;
    const float* src; int o;
    if (k < 2048)      { src = w0 + row * 2048; o = k; }
    else if (k < 3072) { src = w1 + row * 1024; o = k - 2048; }
    else if (k < 3584) { src = w2 + row * 512;  o = k - 3072; }
    else               { src = w3 + row * 768;  o = k - 3584; }
    float4 a = *(const float4*)(src + o);
    float4 b = *(const float4*)(src + o + 4);
    *(bf16x8*)(Wpack + (size_t)u * 8) = cvt8(a, b);
  } else if (bid == 544) {
    int d = threadIdx.x;
    bsum[d] = b0[d] + b1[d] + b2[d] + b3[d];
    cs[d] = 0.f; cq[d] = 0.f;
  } else {
    int i = bid - 545;                   // 0..256
    int o = threadIdx.x;
    if (i < 256) {
      float s = 0.f;
      for (int j = 0; j < 256; ++j)
        s += in_proj_w[(512 + j) * 256 + i] * out_w[o * 256 + j];
      P[i * 256 + o] = s;
    } else {
      float s = 0.f;
      for (int j = 0; j < 256; ++j)
        s += in_proj_b[512 + j] * out_w[o * 256 + j];
      cc[o] = s + out_b[o];
    }
  }
}

// ---- Pre3: GT[j][i] = sum_o (P[i][o]+(i==o))*fc1_w[j][o], pre-swizzled; g[j] ----
__global__ __launch_bounds__(256) void k_pre3(
    const float* __restrict__ P, const float* __restrict__ cc,
    const float* __restrict__ fc1_w, const float* __restrict__ fc1_b,
    bf16* __restrict__ GT, float* __restrict__ g) {
  int j = blockIdx.x;
  int i = threadIdx.x;
  float s = 0.f;
  for (int o = 0; o < 256; ++o)
    s += (P[i * 256 + o] + (i == o ? 1.f : 0.f)) * fc1_w[j * 256 + o];
  int is = (i & ~63) | ((((i >> 3) & 7) ^ (j & 7)) << 3) | (i & 7);
  GT[j * 256 + is] = (bf16)s;
  if (i == 0) {
    float t = 0.f;
    for (int o = 0; o < 256; ++o) t += cc[o] * fc1_w[j * 256 + o];
    g[j] = t + fc1_b[j];
  }
}

// ---- K1: fbar = 0.25*(Xcat @ W^T + bsum). BM=64 BN=256 BK=64 ----
// B: direct-to-VGPR from fragment-packed Wpack (coalesced 1KB/wave/load),
//    reg double-buffered, NO LDS, NO barrier coupling, zero gld_lds.
// A: reg-staged fp32->bf16, tri-buffered LDS (24KB), ONE raw s_barrier/K-step.
__global__ __launch_bounds__(512, 2) void k_gemm1(
    const float* __restrict__ x0, const float* __restrict__ x1,
    const float* __restrict__ x2, const float* __restrict__ x3,
    const bf16* __restrict__ Wpack, const float* __restrict__ bsum,
    bf16* __restrict__ fbar) {
  __shared__ __align__(16) bf16 ldsA[3][4096];   // 3 x 64x64 bf16 = 24 KB
  int mt = blockIdx.x;                           // 256 blocks, 1 per CU
  int tid = threadIdx.x;
  int lane = tid & 63, wid = tid >> 6;           // 8 waves, 1x8: wave tile 64x32
  int fr = lane & 15, fq = lane >> 4;
  f32x4 acc[4][2] = {};

  int arow = tid >> 3, achk = tid & 7;
  int wa = arow * 64 + ((achk ^ (arow & 7)) << 3);
  const size_t xrow = (size_t)(mt * 64 + arow);
  const bf16* wp = Wpack + (size_t)lane * 8;

  float4 arA[2], arB[2];                         // pending A regs (even/odd)
  bf16x8 bbA[2][2], bbB[2][2];                   // B frags (even/odd) [n][kk]

  { // prologue: A(0)->lds slot0, A(1)->arB, B(0)->bbA
    int L, ko; const float* xs = pick(x0, x1, x2, x3, 0, L, ko);
    const float4* ap = (const float4*)(xs + xrow * L + ko) + achk * 2;
    float4 t0 = ap[0], t1 = ap[1];
#pragma unroll
    for (int n = 0; n < 2; ++n)
#pragma unroll
      for (int kk = 0; kk < 2; ++kk)
        bbA[n][kk] = *(const bf16x8*)(wp + ((size_t)((2 * wid + n) * 136 + kk) << 9));
    xs = pick(x0, x1, x2, x3, 64, L, ko);
    ap = (const float4*)(xs + xrow * L + ko) + achk * 2;
    arB[0] = ap[0]; arB[1] = ap[1];
    *(bf16x8*)&ldsA[0][wa] = cvt8(t0, t1);
    __builtin_amdgcn_sched_barrier(0);
    asm volatile("s_waitcnt lgkmcnt(0)" ::: "memory");
    __builtin_amdgcn_s_barrier();
    __builtin_amdgcn_sched_barrier(0);
  }

#define K1_BODY(T, BBU, BBL, ARU, ARL)                                         \
  do {                                                                         \
    int s1 = (s0 == 2) ? 0 : s0 + 1;                                           \
    if ((T) < 67) {                                                            \
      _Pragma("unroll") for (int n = 0; n < 2; ++n)                            \
      _Pragma("unroll") for (int kk = 0; kk < 2; ++kk)                         \
        BBL[n][kk] = *(const bf16x8*)(wp +                                     \
            ((size_t)((2 * wid + n) * 136 + 2 * ((T) + 1) + kk) << 9));        \
    }                                                                          \
    if ((T) < 66) {                                                            \
      int L_, ko_;                                                             \
      const float* xs_ = pick(x0, x1, x2, x3, ((T) + 2) * 64, L_, ko_);        \
      const float4* ap_ = (const float4*)(xs_ + xrow * L_ + ko_) + achk * 2;   \
      ARL[0] = ap_[0]; ARL[1] = ap_[1];                                        \
    }                                                                          \
    if ((T) < 67)                                                              \
      *(bf16x8*)&ldsA[s1][wa] = cvt8(ARU[0], ARU[1]);                          \
    __builtin_amdgcn_sched_barrier(0);                                         \
    asm volatile("s_waitcnt lgkmcnt(0)" ::: "memory");                         \
    __builtin_amdgcn_s_barrier();                                              \
    __builtin_amdgcn_sched_barrier(0);                                         \
    const bf16* A_ = &ldsA[s0][0];                                             \
    bf16x8 av[4][2];                                                           \
    _Pragma("unroll") for (int m = 0; m < 4; ++m) {                            \
      int row_ = m * 16 + fr;                                                  \
      _Pragma("unroll") for (int kk = 0; kk < 2; ++kk) {                       \
        int c_ = (kk << 2) | fq;                                               \
        av[m][kk] = *(const bf16x8*)(A_ + row_ * 64 + ((c_ ^ (row_ & 7)) << 3)); \
      }                                                                        \
    }                                                                          \
    _Pragma("unroll") for (int kk = 0; kk < 2; ++kk)                           \
    _Pragma("unroll") for (int m = 0; m < 4; ++m)                              \
    _Pragma("unroll") for (int n = 0; n < 2; ++n)                              \
      acc[m][n] = __builtin_amdgcn_mfma_f32_16x16x32_bf16(                     \
          av[m][kk], BBU[n][kk], acc[m][n], 0, 0, 0);                          \
    s0 = s1;                                                                   \
  } while (0)

  int s0 = 0;
  for (int tt = 0; tt < 34; ++tt) {              // 68 K-steps, explicit parity
    int t0 = tt * 2;
    K1_BODY(t0,     bbA, bbB, arB, arA);         // even: use bbA/arB, load bbB/arA
    K1_BODY(t0 + 1, bbB, bbA, arA, arB);         // odd : use bbB/arA, load bbA/arB
  }
#undef K1_BODY

#pragma unroll
  for (int n = 0; n < 2; ++n) {
    int col = (2 * wid + n) * 16 + fr;
    float bs = bsum[col];
#pragma unroll
    for (int m = 0; m < 4; ++m) {
      int row0 = mt * 64 + m * 16 + fq * 4;
#pragma unroll
      for (int r = 0; r < 4; ++r) {
        int row = row0 + r;
        int csw = (col & ~63) | ((((col >> 3) & 7) ^ (row & 7)) << 3) | (col & 7);
        fbar[(size_t)row * DM + csw] = (bf16)(0.25f * (acc[m][n][r] + bs));
      }
    }
  }
}

// ---- K2: h = fbar @ GT^T + g (bf16 out) + column stats. K=256, 4 dbuf steps ----
__global__ __launch_bounds__(256, 4) void k_gemm2(
    const bf16* __restrict__ fbar, const bf16* __restrict__ GT,
    const float* __restrict__ g, bf16* __restrict__ h,
    float* __restrict__ cs, float* __restrict__ cq) {
  __shared__ __align__(16) bf16 lds[2][8192];
  int bid = blockIdx.x;
  int tile = (bid & 7) * 128 + (bid >> 3);
  int mt = tile >> 2, nt = tile & 3;
  int tid = threadIdx.x;
  int lane = tid & 63, wid = tid >> 6;
  int wr = wid >> 1, wc = wid & 1;
  int fr = lane & 15, fq = lane >> 4;
  f32x4 acc[2][2] = {};

  const size_t arow0 = (size_t)(mt * 64 + (tid >> 3)) * DM + (tid & 7) * 8;
  const size_t arow1 = (size_t)(mt * 64 + 32 + (tid >> 3)) * DM + (tid & 7) * 8;
  const size_t grow0 = (size_t)(nt * 64 + (tid >> 3)) * DM + (tid & 7) * 8;
  const size_t grow1 = (size_t)(nt * 64 + 32 + (tid >> 3)) * DM + (tid & 7) * 8;

  gld_lds16(fbar + arow0, &lds[0][tid * 8]);
  gld_lds16(fbar + arow1, &lds[0][2048 + tid * 8]);
  gld_lds16(GT + grow0, &lds[0][4096 + tid * 8]);
  gld_lds16(GT + grow1, &lds[0][4096 + 2048 + tid * 8]);
  __syncthreads();

  for (int kt = 0; kt < 4; ++kt) {
    int cur = kt & 1;
    if (kt < 3) {
      int k0 = (kt + 1) * 64;
      gld_lds16(fbar + arow0 + k0, &lds[cur ^ 1][tid * 8]);
      gld_lds16(fbar + arow1 + k0, &lds[cur ^ 1][2048 + tid * 8]);
      gld_lds16(GT + grow0 + k0, &lds[cur ^ 1][4096 + tid * 8]);
      gld_lds16(GT + grow1 + k0, &lds[cur ^ 1][4096 + 2048 + tid * 8]);
    }
    const bf16* A  = &lds[cur][0];
    const bf16* Bb = &lds[cur][4096];
    bf16x8 av[2][2], bv[2][2];
#pragma unroll
    for (int m = 0; m < 2; ++m) {
      int row = wr * 32 + m * 16 + fr;
#pragma unroll
      for (int kk = 0; kk < 2; ++kk)
        av[m][kk] = *(const bf16x8*)(A + row * 64 + ((((kk << 2) | fq) ^ (row & 7)) << 3));
    }
#pragma unroll
    for (int n = 0; n < 2; ++n) {
      int row = wc * 32 + n * 16 + fr;
#pragma unroll
      for (int kk = 0; kk < 2; ++kk)
        bv[n][kk] = *(const bf16x8*)(Bb + row * 64 + ((((kk << 2) | fq) ^ (row & 7)) << 3));
    }
#pragma unroll
    for (int kk = 0; kk < 2; ++kk)
#pragma unroll
      for (int m = 0; m < 2; ++m)
#pragma unroll
        for (int n = 0; n < 2; ++n)
          acc[m][n] = __builtin_amdgcn_mfma_f32_16x16x32_bf16(av[m][kk], bv[n][kk], acc[m][n], 0, 0, 0);
    __syncthreads();
  }

#pragma unroll
  for (int n = 0; n < 2; ++n) {
    int col = nt * 64 + wc * 32 + n * 16 + fr;
    float gv = g[col];
    float s = 0.f, q = 0.f;
#pragma unroll
    for (int m = 0; m < 2; ++m) {
      int row0 = mt * 64 + wr * 32 + m * 16 + fq * 4;
#pragma unroll
      for (int r = 0; r < 4; ++r) {
        float v = acc[m][n][r] + gv;
        h[(size_t)(row0 + r) * DM + col] = (bf16)v;
        s += v; q += v * v;
      }
    }
    s += __shfl_xor(s, 16); s += __shfl_xor(s, 32);
    q += __shfl_xor(q, 16); q += __shfl_xor(q, 32);
    if (fq == 0) { atomicAdd(&cs[col], s); atomicAdd(&cq[col], q); }
  }
}

// ---- stats finalize ----
__global__ void k_stats(const float* __restrict__ cs, const float* __restrict__ cq,
                        const float* __restrict__ bn_g, const float* __restrict__ bn_b,
                        float* __restrict__ sd, float* __restrict__ td) {
  int d = threadIdx.x;
  float mu = cs[d] * (1.f / 16384.f);
  float var = cq[d] * (1.f / 16384.f) - mu * mu;
  float s = bn_g[d] * rsqrtf(var + 1e-5f);
  sd[d] = s;
  td[d] = bn_b[d] - mu * s;
}

// ---- K3: out = relu(h*s + t) @ fc2^T + fc2_b ----
__global__ __launch_bounds__(256) void k_fc2(
    const bf16* __restrict__ h, const float* __restrict__ sd, const float* __restrict__ td,
    const float* __restrict__ fc2_w, const float* __restrict__ fc2_b,
    float* __restrict__ out) {
  int wid = threadIdx.x >> 6, lane = threadIdx.x & 63;
  int row = blockIdx.x * 4 + wid;
  bf16x4 hv = *(const bf16x4*)(h + (size_t)row * 256 + lane * 4);
  float4 s = *(const float4*)(sd + lane * 4);
  float4 t = *(const float4*)(td + lane * 4);
  float y0 = fmaxf((float)hv[0] * s.x + t.x, 0.f);
  float y1 = fmaxf((float)hv[1] * s.y + t.y, 0.f);
  float y2 = fmaxf((float)hv[2] * s.z + t.z, 0.f);
  float y3 = fmaxf((float)hv[3] * s.w + t.w, 0.f);
  for (int c = 0; c < NCLS; ++c) {
    float4 w = *(const float4*)(fc2_w + c * 256 + lane * 4);
    float p = y0 * w.x + y1 * w.y + y2 * w.z + y3 * w.w;
#pragma unroll
    for (int off = 32; off; off >>= 1) p += __shfl_xor(p, off);
    if (lane == 0) out[row * NCLS + c] = p + fc2_b[c];
  }
}

extern "C" void kernel_launch(void* const* d_in, const int* in_sizes, int n_in,
                              void* d_out, int out_size, void* d_ws, size_t ws_size,
                              hipStream_t stream) {
  (void)in_sizes; (void)n_in; (void)out_size; (void)ws_size;
  const float* x0 = (const float*)d_in[0];
  const float* x1 = (const float*)d_in[1];
  const float* x2 = (const float*)d_in[2];
  const float* x3 = (const float*)d_in[3];
  const float* w0 = (const float*)d_in[4];
  const float* b0 = (const float*)d_in[5];
  const float* w1 = (const float*)d_in[6];
  const float* b1 = (const float*)d_in[7];
  const float* w2 = (const float*)d_in[8];
  const float* b2 = (const float*)d_in[9];
  const float* w3 = (const float*)d_in[10];
  const float* b3 = (const float*)d_in[11];
  const float* in_proj_w = (const float*)d_in[12];
  const float* in_proj_b = (const float*)d_in[13];
  const float* out_w = (const float*)d_in[14];
  const float* out_b = (const float*)d_in[15];
  // gate (16..19) is mathematically dead: feats_cross == feats_self
  const float* fc1_w = (const float*)d_in[20];
  const float* fc1_b = (const float*)d_in[21];
  const float* bn_g = (const float*)d_in[22];
  const float* bn_b = (const float*)d_in[23];
  const float* fc2_w = (const float*)d_in[24];
  const float* fc2_b = (const float*)d_in[25];

  char* ws = (char*)d_ws;
  bf16* Wpack = (bf16*)(ws + WPACK_OFF);
  float* P   = (float*)(ws + P_OFF);
  float* cc  = (float*)(ws + CC_OFF);
  bf16* GT   = (bf16*)(ws + GT_OFF);
  float* g   = (float*)(ws + G_OFF);
  float* bsum= (float*)(ws + BSUM_OFF);
  float* cs  = (float*)(ws + CS_OFF);
  float* cq  = (float*)(ws + CQ_OFF);
  float* sd  = (float*)(ws + SD_OFF);
  float* td  = (float*)(ws + TD_OFF);
  bf16* fbar = (bf16*)(ws + FBAR_OFF);
  bf16* h    = (bf16*)(ws + H_OFF);
  float* out = (float*)d_out;

  k_pre12<<<dim3(802), dim3(256), 0, stream>>>(w0, w1, w2, w3, b0, b1, b2, b3,
                                               in_proj_w, in_proj_b, out_w, out_b,
                                               Wpack, bsum, cs, cq, P, cc);
  k_pre3<<<dim3(256), dim3(256), 0, stream>>>(P, cc, fc1_w, fc1_b, GT, g);
  k_gemm1<<<dim3(256), dim3(512), 0, stream>>>(x0, x1, x2, x3, Wpack, bsum, fbar);
  k_gemm2<<<dim3(1024), dim3(256), 0, stream>>>(fbar, GT, g, h, cs, cq);
  k_stats<<<dim3(1), dim3(256), 0, stream>>>(cs, cq, bn_g, bn_b, sd, td);
  k_fc2<<<dim3(4096), dim3(256), 0, stream>>>(h, sd, td, fc2_w, fc2_b, out);
}